// Round 10
// baseline (1024.491 us; speedup 1.0000x reference)
//
#include <hip/hip_runtime.h>
#include <cstddef>

// ---------- constants ----------
#define BATCH 128
#define NV 128          // visits per person
#define CPV 16
#define MAXV 510
#define SPAD 512        // padded sequence
#define DIM 256
#define NH 2
#define DH 128
#define NLAYERS 2
#define DFF 1024
#define MROWS (BATCH * SPAD)   // 65536

typedef __attribute__((ext_vector_type(8))) short short8;
typedef __attribute__((ext_vector_type(4))) short short4v;
typedef __attribute__((ext_vector_type(4))) float floatx4;

__device__ __forceinline__ short f2bf(float f) {
    union { float f; unsigned u; } v; v.f = f;
    unsigned r = v.u + 0x7fffu + ((v.u >> 16) & 1u);
    return (short)(r >> 16);
}
__device__ __forceinline__ float bf2f(short s) {
    union { unsigned u; float f; } v; v.u = ((unsigned)(unsigned short)s) << 16;
    return v.f;
}

__device__ __forceinline__ void gload_lds16(const short* g, short* l) {
    __builtin_amdgcn_global_load_lds(
        (const __attribute__((address_space(1))) unsigned int*)g,
        (__attribute__((address_space(3))) unsigned int*)l,
        16, 0, 0);
}

// ---------- weight transpose: src f32 [K,N] -> dst bf16 [N,K] ----------
__global__ __launch_bounds__(256) void wtrans(const float* __restrict__ src,
                                              short* __restrict__ dst,
                                              int K, int N) {
    int idx = blockIdx.x * 256 + threadIdx.x;
    if (idx >= K * N) return;
    int k = idx / N, n = idx - k * N;
    dst[(size_t)n * K + k] = f2bf(src[idx]);
}

// ---------- build x (known-good) ----------
__global__ __launch_bounds__(256) void build_x(const int* __restrict__ codes,
                                               const float* __restrict__ times,
                                               const float* __restrict__ cemb,
                                               const float* __restrict__ pemb,
                                               short* __restrict__ x) {
    int row = blockIdx.x;          // b*512 + p
    int d = threadIdx.x;
    int b = row >> 9;
    int p = row & 511;
    float val;
    if (p >= MAXV) {
        val = 0.f;
    } else if (p < MAXV - NV) {
        val = pemb[d];
    } else {
        int visit = b * NV + (p - (MAXV - NV));
        const int* cb = codes + visit * CPV;
        float s = 0.f;
#pragma unroll
        for (int c = 0; c < CPV; ++c)
            s += cemb[(size_t)cb[c] * DIM + d];
        float t = times[visit];
        t = fminf(fmaxf(t, 0.f), 364.f);
        int i = d & 127;
        float ang = t * expf(-0.03597789207803197f * (float)i);
        float te = (d < 128) ? sinf(ang) : cosf(ang);
        val = s + te;
    }
    x[(size_t)row * DIM + d] = f2bf(val);
}

// ---------- merged QKV GEMM: BT = [WqT; WkT; WvT] (768 x 256) ----------
__global__ __launch_bounds__(256) void gemm_qkv(const short* __restrict__ A,
                                                const short* __restrict__ BT,
                                                const float* __restrict__ bq,
                                                const float* __restrict__ bk,
                                                const float* __restrict__ bv,
                                                short* __restrict__ qo,
                                                short* __restrict__ ko,
                                                short* __restrict__ vo) {
    __shared__ __align__(16) short lA[128 * 32];
    __shared__ __align__(16) short lB[128 * 32];
    int tid = threadIdx.x;
    int wave = tid >> 6, lane = tid & 63;
    int l15 = lane & 15, quad = lane >> 4;
    int q8 = quad * 8;
    int m0 = blockIdx.y * 128;
    int n0 = blockIdx.x * 128;            // 0..640
    int sel = blockIdx.x >> 1;            // 0=q 1=k 2=v
    int nloc = n0 & 255;
    int wm = (wave & 1) * 64;
    int wn = (wave >> 1) * 64;

    int srow = tid >> 2;
    int skoff = (tid & 3) * 8;
    const short* ag = A + (size_t)(m0 + srow) * DIM + skoff;
    const short* bg = BT + (size_t)(n0 + srow) * DIM + skoff;
    short* lA_dst = lA + tid * 8;
    short* lB_dst = lB + tid * 8;
    const size_t rstep = (size_t)64 * DIM;

    floatx4 acc[4][4];
#pragma unroll
    for (int i = 0; i < 4; ++i)
#pragma unroll
        for (int j = 0; j < 4; ++j) acc[i][j] = (floatx4){0.f, 0.f, 0.f, 0.f};

#pragma unroll
    for (int k0 = 0; k0 < DIM; k0 += 32) {
        gload_lds16(ag + k0, lA_dst);
        gload_lds16(ag + rstep + k0, lA_dst + 2048);
        gload_lds16(bg + k0, lB_dst);
        gload_lds16(bg + rstep + k0, lB_dst + 2048);
        __syncthreads();
        short8 aF[4], bF[4];
#pragma unroll
        for (int t = 0; t < 4; ++t) {
            aF[t] = *(const short8*)(lA + (wm + t * 16 + l15) * 32 + q8);
            bF[t] = *(const short8*)(lB + (wn + t * 16 + l15) * 32 + q8);
        }
#pragma unroll
        for (int i = 0; i < 4; ++i)
#pragma unroll
            for (int j = 0; j < 4; ++j)
                acc[i][j] = __builtin_amdgcn_mfma_f32_16x16x32_bf16(aF[i], bF[j], acc[i][j], 0, 0, 0);
        __syncthreads();
    }

    const float* bias = (sel == 0) ? bq : (sel == 1) ? bk : bv;
    short* out = (sel == 0) ? qo : (sel == 1) ? ko : vo;
#pragma unroll
    for (int j = 0; j < 4; ++j) {
        int col = nloc + wn + j * 16 + l15;
        float bval = bias[col];
#pragma unroll
        for (int i = 0; i < 4; ++i) {
#pragma unroll
            for (int r = 0; r < 4; ++r) {
                int row = m0 + wm + i * 16 + quad * 4 + r;
                out[(size_t)row * DIM + col] = f2bf(acc[i][j][r] + bval);
            }
        }
    }
}

// ---------- Wo projection + residual + LN1, fused. NON-ALIASED: X != xout ----------
__global__ __launch_bounds__(256) void gemm_wo_ln(const short* __restrict__ CTX,
                                                  const short* __restrict__ WoT,
                                                  const float* __restrict__ bo,
                                                  const short* __restrict__ X,
                                                  const float* __restrict__ g,
                                                  const float* __restrict__ bta,
                                                  short* __restrict__ xout) {
    __shared__ __align__(16) short lA[128 * 32];   // ctx k-slice     8 KiB
    __shared__ __align__(16) short lB[256 * 32];   // WoT k-slice    16 KiB
    int tid = threadIdx.x;
    int wave = tid >> 6, lane = tid & 63;
    int l15 = lane & 15, quad = lane >> 4;
    int q8 = quad * 8;
    int m0 = blockIdx.x * 128;
    int wr = wave * 32;
    int srow = tid >> 2;
    int skoff = (tid & 3) * 8;
    const short* ag = CTX + (size_t)(m0 + srow) * DIM + skoff;
    const short* bg = WoT + (size_t)srow * DIM + skoff;
    short* lA_dst = lA + tid * 8;
    short* lB_dst = lB + tid * 8;

    floatx4 acc[2][16];
#pragma unroll
    for (int i = 0; i < 2; ++i)
#pragma unroll
        for (int j = 0; j < 16; ++j) acc[i][j] = (floatx4){0.f, 0.f, 0.f, 0.f};

#pragma unroll
    for (int k0 = 0; k0 < DIM; k0 += 32) {
        gload_lds16(ag + k0, lA_dst);
        gload_lds16(ag + (size_t)64 * DIM + k0, lA_dst + 2048);
        gload_lds16(bg + k0, lB_dst);
        gload_lds16(bg + (size_t)64 * DIM + k0, lB_dst + 2048);
        gload_lds16(bg + (size_t)128 * DIM + k0, lB_dst + 4096);
        gload_lds16(bg + (size_t)192 * DIM + k0, lB_dst + 6144);
        __syncthreads();
        short8 aF[2];
#pragma unroll
        for (int t = 0; t < 2; ++t)
            aF[t] = *(const short8*)(lA + (wr + t * 16 + l15) * 32 + q8);
#pragma unroll
        for (int j = 0; j < 16; ++j) {
            short8 bF = *(const short8*)(lB + (j * 16 + l15) * 32 + q8);
#pragma unroll
            for (int i = 0; i < 2; ++i)
                acc[i][j] = __builtin_amdgcn_mfma_f32_16x16x32_bf16(aF[i], bF, acc[i][j], 0, 0, 0);
        }
        __syncthreads();
    }

    float bias[16], gam[16], bet[16];
#pragma unroll
    for (int j = 0; j < 16; ++j) {
        int col = j * 16 + l15;
        bias[j] = bo[col]; gam[j] = g[col]; bet[j] = bta[col];
    }
#pragma unroll
    for (int i = 0; i < 2; ++i) {
#pragma unroll
        for (int r = 0; r < 4; ++r) {
            int row = m0 + wr + i * 16 + quad * 4 + r;
            float v[16], s = 0.f, sq = 0.f;
#pragma unroll
            for (int j = 0; j < 16; ++j) {
                v[j] = acc[i][j][r] + bias[j] + bf2f(X[(size_t)row * DIM + j * 16 + l15]);
                s += v[j]; sq += v[j] * v[j];
            }
            s += __shfl_xor(s, 1); sq += __shfl_xor(sq, 1);
            s += __shfl_xor(s, 2); sq += __shfl_xor(sq, 2);
            s += __shfl_xor(s, 4); sq += __shfl_xor(sq, 4);
            s += __shfl_xor(s, 8); sq += __shfl_xor(sq, 8);
            float mean = s * (1.f / 256.f);
            float var = fmaxf(sq * (1.f / 256.f) - mean * mean, 0.f);
            float rstd = rsqrtf(var + 1e-5f);
#pragma unroll
            for (int j = 0; j < 16; ++j) {
                float y = gam[j] * (v[j] - mean) * rstd + bet[j];
                xout[(size_t)row * DIM + j * 16 + l15] = f2bf(y);
            }
        }
    }
}

// ---------- fused FFN + residual + LN2: GEMM structure IDENTICAL to the
// round-8-passing ff_fused (acc2[4][8], wm/wn2 layout). LN2 is done in the
// epilogue via cross-wave LDS reduction (ln_k's proven pattern): each wave
// holds a 64-row x 128-col half; per-quad shuffle gives half-row sums; the
// two halves combine through a 2 KiB LDS table + one barrier.
#define PST 136
__global__ __launch_bounds__(256, 2) void ff_fused_ln2(const short* __restrict__ X,
                                                       const short* __restrict__ W1T,
                                                       const float* __restrict__ b1,
                                                       const short* __restrict__ W2T,
                                                       const float* __restrict__ b2,
                                                       const float* __restrict__ g,
                                                       const float* __restrict__ bta,
                                                       short* __restrict__ xout,
                                                       float* __restrict__ fout) {
    __shared__ __align__(16) short lA[128 * 32];     // x k-slice      8 KiB
    __shared__ __align__(16) short lB[128 * 32];     // W1T k-slice    8 KiB
    __shared__ __align__(16) short lB2[256 * 32];    // W2T k-slice   16 KiB
    __shared__ __align__(16) short lP[128 * PST];    // relu(ff1)     34 KiB
    __shared__ float lred[128][2][2];                // (s,sq) per row,half  2 KiB
    int tid = threadIdx.x;
    int wave = tid >> 6, lane = tid & 63;
    int l15 = lane & 15, quad = lane >> 4;
    int q8 = quad * 8;
    int m0 = blockIdx.x * 128;
    int wm = (wave & 1) * 64;        // row quadrant (both GEMMs)
    int wf = (wave >> 1) * 64;       // dff cols (GEMM1)
    int wn2 = (wave >> 1) * 128;     // out cols (GEMM2)
    int half = wave >> 1;            // which 128-col half this wave owns
    int srow = tid >> 2;
    int spart = (tid & 3) * 8;
    const short* xg = X + (size_t)(m0 + srow) * DIM + spart;
    short* lA_dst = lA + tid * 8;
    short* lB_dst = lB + tid * 8;
    short* lB2_dst = lB2 + tid * 8;

    floatx4 acc2[4][8];
#pragma unroll
    for (int i = 0; i < 4; ++i)
#pragma unroll
        for (int j = 0; j < 8; ++j) acc2[i][j] = (floatx4){0.f, 0.f, 0.f, 0.f};

    for (int f0 = 0; f0 < DFF; f0 += 128) {
        // ---- GEMM1: P = relu(x @ W1[:, f0:f0+128] + b1) ----
        const short* w1g = W1T + (size_t)(f0 + srow) * DIM + spart;
        floatx4 acc1[4][4];
#pragma unroll
        for (int i = 0; i < 4; ++i)
#pragma unroll
            for (int j = 0; j < 4; ++j) acc1[i][j] = (floatx4){0.f, 0.f, 0.f, 0.f};
#pragma unroll
        for (int k0 = 0; k0 < DIM; k0 += 32) {
            gload_lds16(xg + k0, lA_dst);
            gload_lds16(xg + (size_t)64 * DIM + k0, lA_dst + 2048);
            gload_lds16(w1g + k0, lB_dst);
            gload_lds16(w1g + (size_t)64 * DIM + k0, lB_dst + 2048);
            __syncthreads();
            short8 aF[4], bF[4];
#pragma unroll
            for (int t = 0; t < 4; ++t) {
                aF[t] = *(const short8*)(lA + (wm + t * 16 + l15) * 32 + q8);
                bF[t] = *(const short8*)(lB + (wf + t * 16 + l15) * 32 + q8);
            }
#pragma unroll
            for (int i = 0; i < 4; ++i)
#pragma unroll
                for (int j = 0; j < 4; ++j)
                    acc1[i][j] = __builtin_amdgcn_mfma_f32_16x16x32_bf16(aF[i], bF[j], acc1[i][j], 0, 0, 0);
            __syncthreads();
        }
        // bias + relu -> lP
#pragma unroll
        for (int j = 0; j < 4; ++j) {
            int fc = wf + j * 16 + l15;
            float bval = b1[f0 + fc];
#pragma unroll
            for (int i = 0; i < 4; ++i) {
#pragma unroll
                for (int r = 0; r < 4; ++r) {
                    float v = acc1[i][j][r] + bval;
                    lP[(wm + i * 16 + quad * 4 + r) * PST + fc] = f2bf(fmaxf(v, 0.f));
                }
            }
        }
        __syncthreads();
        // ---- GEMM2: acc2 += P @ W2[f0:f0+128, :] ----
#pragma unroll
        for (int ks = 0; ks < 4; ++ks) {
            const short* w2g = W2T + (size_t)srow * DFF + f0 + ks * 32 + spart;
            gload_lds16(w2g, lB2_dst);
            gload_lds16(w2g + (size_t)64 * DFF, lB2_dst + 2048);
            gload_lds16(w2g + (size_t)128 * DFF, lB2_dst + 4096);
            gload_lds16(w2g + (size_t)192 * DFF, lB2_dst + 6144);
            __syncthreads();
            short8 aP[4], bW[8];
#pragma unroll
            for (int t = 0; t < 4; ++t)
                aP[t] = *(const short8*)(lP + (wm + t * 16 + l15) * PST + ks * 32 + q8);
#pragma unroll
            for (int j = 0; j < 8; ++j)
                bW[j] = *(const short8*)(lB2 + (wn2 + j * 16 + l15) * 32 + q8);
#pragma unroll
            for (int i = 0; i < 4; ++i)
#pragma unroll
                for (int j = 0; j < 8; ++j)
                    acc2[i][j] = __builtin_amdgcn_mfma_f32_16x16x32_bf16(aP[i], bW[j], acc2[i][j], 0, 0, 0);
            __syncthreads();
        }
    }

    // ---- epilogue: h2 = acc2 + b2 + X; LN2 via cross-wave LDS reduce ----
    // fold bias + residual into acc2
#pragma unroll
    for (int j = 0; j < 8; ++j) {
        int col = wn2 + j * 16 + l15;
        float bval = b2[col];
#pragma unroll
        for (int i = 0; i < 4; ++i) {
#pragma unroll
            for (int r = 0; r < 4; ++r) {
                int row = m0 + wm + i * 16 + quad * 4 + r;
                acc2[i][j][r] += bval + bf2f(X[(size_t)row * DIM + col]);
            }
        }
    }
    // per-(row) half sums -> lred[row][half]
#pragma unroll
    for (int i = 0; i < 4; ++i) {
#pragma unroll
        for (int r = 0; r < 4; ++r) {
            float s = 0.f, sq = 0.f;
#pragma unroll
            for (int j = 0; j < 8; ++j) {
                float v = acc2[i][j][r];
                s += v; sq += v * v;
            }
            s += __shfl_xor(s, 1); sq += __shfl_xor(sq, 1);
            s += __shfl_xor(s, 2); sq += __shfl_xor(sq, 2);
            s += __shfl_xor(s, 4); sq += __shfl_xor(sq, 4);
            s += __shfl_xor(s, 8); sq += __shfl_xor(sq, 8);
            if (l15 == 0) {
                int lrow = wm + i * 16 + quad * 4 + r;
                lred[lrow][half][0] = s;
                lred[lrow][half][1] = sq;
            }
        }
    }
    __syncthreads();
    // normalize + write
    float gam[8], bet[8];
#pragma unroll
    for (int j = 0; j < 8; ++j) {
        int col = wn2 + j * 16 + l15;
        gam[j] = g[col]; bet[j] = bta[col];
    }
#pragma unroll
    for (int i = 0; i < 4; ++i) {
#pragma unroll
        for (int r = 0; r < 4; ++r) {
            int lrow = wm + i * 16 + quad * 4 + r;
            int row = m0 + lrow;
            float s = lred[lrow][0][0] + lred[lrow][1][0];
            float sq = lred[lrow][0][1] + lred[lrow][1][1];
            float mean = s * (1.f / 256.f);
            float var = fmaxf(sq * (1.f / 256.f) - mean * mean, 0.f);
            float rstd = rsqrtf(var + 1e-5f);
            int p = row & 511;
            int bb = row >> 9;
#pragma unroll
            for (int j = 0; j < 8; ++j) {
                int col = wn2 + j * 16 + l15;
                float y = gam[j] * (acc2[i][j][r] - mean) * rstd + bet[j];
                xout[(size_t)row * DIM + col] = f2bf(y);
                if (fout && p < MAXV)
                    fout[((size_t)bb * MAXV + p) * DIM + col] = y;
            }
        }
    }
}

// ---------- V transpose: v [M,256] -> vT [B*H][DH][SPAD] ----------
__global__ __launch_bounds__(256) void transpose_v(const short* __restrict__ v,
                                                   short* __restrict__ vT) {
    __shared__ short lds[32][33];
    int pair = blockIdx.y;
    int b = pair >> 1, h = pair & 1;
    int st = (blockIdx.x & 15) * 32;
    int dt = (blockIdx.x >> 4) * 32;
    int tid = threadIdx.x;
    int sl = tid >> 3, dl = (tid & 7) * 4;
    const short* src = v + ((size_t)(b * SPAD + st + sl)) * DIM + h * DH + dt + dl;
    short4v val = *(const short4v*)src;
#pragma unroll
    for (int j = 0; j < 4; ++j) lds[sl][dl + j] = val[j];
    __syncthreads();
    int drow = tid >> 3, scol = (tid & 7) * 4;
    short* dst = vT + (size_t)pair * DH * SPAD + (size_t)(dt + drow) * SPAD + st + scol;
#pragma unroll
    for (int j = 0; j < 4; ++j) dst[j] = lds[scol + j][drow];
}

// ---------- attention pass A: S = exp(scale * Q K^T), masked ----------
__global__ __launch_bounds__(256) void score_exp(const short* __restrict__ q,
                                                 const short* __restrict__ k,
                                                 short* __restrict__ S,
                                                 int p0) {
    __shared__ __align__(16) short lA[128 * 32];
    __shared__ __align__(16) short lB[128 * 32];
    int tid = threadIdx.x;
    int wave = tid >> 6, lane = tid & 63;
    int l15 = lane & 15, quad = lane >> 4;
    int q8 = quad * 8;
    int pl = blockIdx.z;
    int pair = p0 + pl;
    int b = pair >> 1, h = pair & 1;
    int m0 = blockIdx.y * 128;
    int n0 = blockIdx.x * 128;
    int wm = (wave & 1) * 64;
    int wn = (wave >> 1) * 64;

    const short* Qb = q + ((size_t)b * SPAD) * DIM + h * DH;
    const short* Kb = k + ((size_t)b * SPAD) * DIM + h * DH;
    int srow = tid >> 2;
    int skoff = (tid & 3) * 8;
    const short* ag = Qb + (size_t)(m0 + srow) * DIM + skoff;
    const short* bg = Kb + (size_t)(n0 + srow) * DIM + skoff;
    short* lA_dst = lA + tid * 8;
    short* lB_dst = lB + tid * 8;
    const size_t rstep = (size_t)64 * DIM;

    floatx4 acc[4][4];
#pragma unroll
    for (int i = 0; i < 4; ++i)
#pragma unroll
        for (int j = 0; j < 4; ++j) acc[i][j] = (floatx4){0.f, 0.f, 0.f, 0.f};

#pragma unroll
    for (int k0 = 0; k0 < DH; k0 += 32) {
        gload_lds16(ag + k0, lA_dst);
        gload_lds16(ag + rstep + k0, lA_dst + 2048);
        gload_lds16(bg + k0, lB_dst);
        gload_lds16(bg + rstep + k0, lB_dst + 2048);
        __syncthreads();
        short8 aF[4], bF[4];
#pragma unroll
        for (int t = 0; t < 4; ++t) {
            aF[t] = *(const short8*)(lA + (wm + t * 16 + l15) * 32 + q8);
            bF[t] = *(const short8*)(lB + (wn + t * 16 + l15) * 32 + q8);
        }
#pragma unroll
        for (int i = 0; i < 4; ++i)
#pragma unroll
            for (int j = 0; j < 4; ++j)
                acc[i][j] = __builtin_amdgcn_mfma_f32_16x16x32_bf16(aF[i], bF[j], acc[i][j], 0, 0, 0);
        __syncthreads();
    }

    const float scale = 0.08838834764831845f;  // 1/sqrt(128)
    short* Sp = S + (size_t)pl * SPAD * SPAD;
#pragma unroll
    for (int j = 0; j < 4; ++j) {
        int col = n0 + wn + j * 16 + l15;
        float keep = (col < MAXV) ? 1.f : 0.f;
#pragma unroll
        for (int i = 0; i < 4; ++i) {
#pragma unroll
            for (int r = 0; r < 4; ++r) {
                int row = m0 + wm + i * 16 + quad * 4 + r;
                Sp[(size_t)row * SPAD + col] = f2bf(keep * __expf(acc[i][j][r] * scale));
            }
        }
    }
}

// ---------- attention pass B: ctx = (S @ V) / rowsum(S) ----------
__global__ __launch_bounds__(256) void attn_pv(const short* __restrict__ S,
                                               const short* __restrict__ vT,
                                               short* __restrict__ ctx,
                                               int p0) {
    __shared__ __align__(16) short lA[128 * 32];
    __shared__ __align__(16) short lB[128 * 32];
    int tid = threadIdx.x;
    int wave = tid >> 6, lane = tid & 63;
    int l15 = lane & 15, quad = lane >> 4;
    int q8 = quad * 8;
    int pl = blockIdx.z;
    int pair = p0 + pl;
    int b = pair >> 1, h = pair & 1;
    int m0 = blockIdx.y * 128;
    int wm = (wave & 1) * 64;
    int wn = (wave >> 1) * 64;

    const short* Ab = S + (size_t)pl * SPAD * SPAD;
    const short* Bb = vT + (size_t)pair * DH * SPAD;
    int srow = tid >> 2;
    int skoff = (tid & 3) * 8;
    const short* ag = Ab + (size_t)(m0 + srow) * SPAD + skoff;
    const short* bg = Bb + (size_t)srow * SPAD + skoff;
    short* lA_dst = lA + tid * 8;
    short* lB_dst = lB + tid * 8;
    const size_t rstepA = (size_t)64 * SPAD;
    const size_t rstepB = (size_t)64 * SPAD;

    floatx4 acc[4][4];
#pragma unroll
    for (int i = 0; i < 4; ++i)
#pragma unroll
        for (int j = 0; j < 4; ++j) acc[i][j] = (floatx4){0.f, 0.f, 0.f, 0.f};
    float rsum[4] = {0.f, 0.f, 0.f, 0.f};

    for (int k0 = 0; k0 < SPAD; k0 += 32) {
        gload_lds16(ag + k0, lA_dst);
        gload_lds16(ag + rstepA + k0, lA_dst + 2048);
        gload_lds16(bg + k0, lB_dst);
        gload_lds16(bg + rstepB + k0, lB_dst + 2048);
        __syncthreads();
        short8 aF[4], bF[4];
#pragma unroll
        for (int t = 0; t < 4; ++t) {
            aF[t] = *(const short8*)(lA + (wm + t * 16 + l15) * 32 + q8);
            bF[t] = *(const short8*)(lB + (wn + t * 16 + l15) * 32 + q8);
        }
#pragma unroll
        for (int i = 0; i < 4; ++i) {
            float s = 0.f;
#pragma unroll
            for (int e = 0; e < 8; ++e) s += bf2f(aF[i][e]);
            rsum[i] += s;
        }
#pragma unroll
        for (int i = 0; i < 4; ++i)
#pragma unroll
            for (int j = 0; j < 4; ++j)
                acc[i][j] = __builtin_amdgcn_mfma_f32_16x16x32_bf16(aF[i], bF[j], acc[i][j], 0, 0, 0);
        __syncthreads();
    }

#pragma unroll
    for (int i = 0; i < 4; ++i) {
        rsum[i] += __shfl_xor(rsum[i], 16);
        rsum[i] += __shfl_xor(rsum[i], 32);
    }
    short* outb = ctx + ((size_t)(b * SPAD + m0)) * DIM + h * DH;
#pragma unroll
    for (int i = 0; i < 4; ++i) {
#pragma unroll
        for (int r = 0; r < 4; ++r) {
            float inv = 1.f / __shfl(rsum[i], quad * 4 + r);
#pragma unroll
            for (int j = 0; j < 4; ++j) {
                int col = wn + j * 16 + l15;
                int row = wm + i * 16 + quad * 4 + r;
                outb[(size_t)row * DIM + col] = f2bf(acc[i][j][r] * inv);
            }
        }
    }
}

extern "C" void kernel_launch(void* const* d_in, const int* in_sizes, int n_in,
                              void* d_out, int out_size, void* d_ws, size_t ws_size,
                              hipStream_t stream) {
    const int*   all_codes = (const int*)d_in[0];
    const float* times = (const float*)d_in[3];
    const float* cemb  = (const float*)d_in[4];
    const float* pemb  = (const float*)d_in[5];
    const float* Wq = (const float*)d_in[6];
    const float* Wk = (const float*)d_in[7];
    const float* Wv = (const float*)d_in[8];
    const float* Wo = (const float*)d_in[9];
    const float* bq = (const float*)d_in[10];
    const float* bk = (const float*)d_in[11];
    const float* bv = (const float*)d_in[12];
    const float* bo = (const float*)d_in[13];
    const float* ln1g = (const float*)d_in[14];
    const float* ln1b = (const float*)d_in[15];
    const float* W1 = (const float*)d_in[16];
    const float* b1 = (const float*)d_in[17];
    const float* W2 = (const float*)d_in[18];
    const float* b2 = (const float*)d_in[19];
    const float* ln2g = (const float*)d_in[20];
    const float* ln2b = (const float*)d_in[21];

    char* ws = (char*)d_ws;
    short* wqkvT = (short*)ws;                    // [2][768*256]
    short* woT   = wqkvT + 2 * 196608;            // [2][256*256]
    short* w1T   = woT + 2 * 65536;               // [2][1024*256]
    short* w2T   = w1T + 2 * 262144;              // [2][256*1024]

    const size_t SLOT = (size_t)MROWS * DIM;
    short* xb = (short*)(ws + (4u << 20));
    short* C0 = xb + SLOT;     // q -> h1 (LN1 out)
    short* C1 = C0 + SLOT;     // k
    short* C2 = C1 + SLOT;     // v (dead after transpose -> S fallback)
    short* C3 = C2 + SLOT;     // ctx
    short* C4 = C3 + SLOT;     // vT
    short* Sext = C4 + SLOT;   // big S region if workspace allows

    const size_t base_bytes = (4u << 20) + 6 * SLOT * sizeof(short);
    int chp; short* Sbuf;
    if (ws_size >= base_bytes + (size_t)256 * SPAD * SPAD * 2) { chp = 256; Sbuf = Sext; }
    else if (ws_size >= base_bytes + (size_t)128 * SPAD * SPAD * 2) { chp = 128; Sbuf = Sext; }
    else { chp = 64; Sbuf = C2; }

    for (int l = 0; l < NLAYERS; ++l) {
        short* qkv_l = wqkvT + (size_t)l * 196608;
        wtrans<<<256, 256, 0, stream>>>(Wq + (size_t)l * 65536, qkv_l, 256, 256);
        wtrans<<<256, 256, 0, stream>>>(Wk + (size_t)l * 65536, qkv_l + 65536, 256, 256);
        wtrans<<<256, 256, 0, stream>>>(Wv + (size_t)l * 65536, qkv_l + 131072, 256, 256);
        wtrans<<<256, 256, 0, stream>>>(Wo + (size_t)l * 65536, woT + (size_t)l * 65536, 256, 256);
        wtrans<<<1024, 256, 0, stream>>>(W1 + (size_t)l * 262144, w1T + (size_t)l * 262144, 256, 1024);
        wtrans<<<1024, 256, 0, stream>>>(W2 + (size_t)l * 262144, w2T + (size_t)l * 262144, 1024, 256);
    }

    build_x<<<MROWS, 256, 0, stream>>>(all_codes, times, cemb, pemb, xb);

    for (int l = 0; l < NLAYERS; ++l) {
        const short* qkv_l = wqkvT + (size_t)l * 196608;
        const short* wo_l = woT + (size_t)l * 65536;
        const short* w1_l = w1T + (size_t)l * 262144;
        const short* w2_l = w2T + (size_t)l * 262144;

        gemm_qkv<<<dim3(6, 512), 256, 0, stream>>>(xb, qkv_l, bq + l * 256, bk + l * 256,
                                                   bv + l * 256, C0, C1, C2);
        transpose_v<<<dim3(64, BATCH * NH), 256, 0, stream>>>(C2, C4);
        for (int c = 0; c < BATCH * NH; c += chp) {
            score_exp<<<dim3(4, 4, chp), 256, 0, stream>>>(C0, C1, Sbuf, c);
            attn_pv<<<dim3(1, 4, chp), 256, 0, stream>>>(Sbuf, C4, C3, c);
        }
        // h1 = LN1(x + ctx@Wo + bo): reads C3 + xb, writes C0. No aliasing.
        gemm_wo_ln<<<512, 256, 0, stream>>>(C3, wo_l, bo + l * 256, xb,
                                            ln1g + l * 256, ln1b + l * 256, C0);
        // x' = LN2(h1 + ffn(h1)): reads C0, writes xb (+ f32 d_out). No aliasing.
        ff_fused_ln2<<<512, 256, 0, stream>>>(C0, w1_l, b1 + l * 1024, w2_l, b2 + l * 256,
                                              ln2g + l * 256, ln2b + l * 256, xb,
                                              (l == NLAYERS - 1) ? (float*)d_out : nullptr);
    }
}

// Round 11
// 856.801 us; speedup vs baseline: 1.1957x; 1.1957x over previous
//
#include <hip/hip_runtime.h>
#include <cstddef>

// ---------- constants ----------
#define BATCH 128
#define NV 128          // visits per person
#define CPV 16
#define MAXV 510
#define SPAD 512        // padded sequence
#define DIM 256
#define NH 2
#define DH 128
#define NLAYERS 2
#define DFF 1024
#define MROWS (BATCH * SPAD)   // 65536

typedef __attribute__((ext_vector_type(8))) short short8;
typedef __attribute__((ext_vector_type(4))) short short4v;
typedef __attribute__((ext_vector_type(4))) float floatx4;

__device__ __forceinline__ short f2bf(float f) {
    union { float f; unsigned u; } v; v.f = f;
    unsigned r = v.u + 0x7fffu + ((v.u >> 16) & 1u);
    return (short)(r >> 16);
}
__device__ __forceinline__ float bf2f(short s) {
    union { unsigned u; float f; } v; v.u = ((unsigned)(unsigned short)s) << 16;
    return v.f;
}

__device__ __forceinline__ void gload_lds16(const short* g, short* l) {
    __builtin_amdgcn_global_load_lds(
        (const __attribute__((address_space(1))) unsigned int*)g,
        (__attribute__((address_space(3))) unsigned int*)l,
        16, 0, 0);
}

// ---------- weight transpose: src f32 [K,N] -> dst bf16 [N,K] ----------
__global__ __launch_bounds__(256) void wtrans(const float* __restrict__ src,
                                              short* __restrict__ dst,
                                              int K, int N) {
    int idx = blockIdx.x * 256 + threadIdx.x;
    if (idx >= K * N) return;
    int k = idx / N, n = idx - k * N;
    dst[(size_t)n * K + k] = f2bf(src[idx]);
}

// ---------- build x (known-good) ----------
__global__ __launch_bounds__(256) void build_x(const int* __restrict__ codes,
                                               const float* __restrict__ times,
                                               const float* __restrict__ cemb,
                                               const float* __restrict__ pemb,
                                               short* __restrict__ x) {
    int row = blockIdx.x;          // b*512 + p
    int d = threadIdx.x;
    int b = row >> 9;
    int p = row & 511;
    float val;
    if (p >= MAXV) {
        val = 0.f;
    } else if (p < MAXV - NV) {
        val = pemb[d];
    } else {
        int visit = b * NV + (p - (MAXV - NV));
        const int* cb = codes + visit * CPV;
        float s = 0.f;
#pragma unroll
        for (int c = 0; c < CPV; ++c)
            s += cemb[(size_t)cb[c] * DIM + d];
        float t = times[visit];
        t = fminf(fmaxf(t, 0.f), 364.f);
        int i = d & 127;
        float ang = t * expf(-0.03597789207803197f * (float)i);
        float te = (d < 128) ? sinf(ang) : cosf(ang);
        val = s + te;
    }
    x[(size_t)row * DIM + d] = f2bf(val);
}

// ---------- merged QKV GEMM: BT = [WqT; WkT; WvT] (768 x 256) ----------
__global__ __launch_bounds__(256) void gemm_qkv(const short* __restrict__ A,
                                                const short* __restrict__ BT,
                                                const float* __restrict__ bq,
                                                const float* __restrict__ bk,
                                                const float* __restrict__ bv,
                                                short* __restrict__ qo,
                                                short* __restrict__ ko,
                                                short* __restrict__ vo) {
    __shared__ __align__(16) short lA[128 * 32];
    __shared__ __align__(16) short lB[128 * 32];
    int tid = threadIdx.x;
    int wave = tid >> 6, lane = tid & 63;
    int l15 = lane & 15, quad = lane >> 4;
    int q8 = quad * 8;
    int m0 = blockIdx.y * 128;
    int n0 = blockIdx.x * 128;            // 0..640
    int sel = blockIdx.x >> 1;            // 0=q 1=k 2=v
    int nloc = n0 & 255;
    int wm = (wave & 1) * 64;
    int wn = (wave >> 1) * 64;

    int srow = tid >> 2;
    int skoff = (tid & 3) * 8;
    const short* ag = A + (size_t)(m0 + srow) * DIM + skoff;
    const short* bg = BT + (size_t)(n0 + srow) * DIM + skoff;
    short* lA_dst = lA + tid * 8;
    short* lB_dst = lB + tid * 8;
    const size_t rstep = (size_t)64 * DIM;

    floatx4 acc[4][4];
#pragma unroll
    for (int i = 0; i < 4; ++i)
#pragma unroll
        for (int j = 0; j < 4; ++j) acc[i][j] = (floatx4){0.f, 0.f, 0.f, 0.f};

#pragma unroll
    for (int k0 = 0; k0 < DIM; k0 += 32) {
        gload_lds16(ag + k0, lA_dst);
        gload_lds16(ag + rstep + k0, lA_dst + 2048);
        gload_lds16(bg + k0, lB_dst);
        gload_lds16(bg + rstep + k0, lB_dst + 2048);
        __syncthreads();
        short8 aF[4], bF[4];
#pragma unroll
        for (int t = 0; t < 4; ++t) {
            aF[t] = *(const short8*)(lA + (wm + t * 16 + l15) * 32 + q8);
            bF[t] = *(const short8*)(lB + (wn + t * 16 + l15) * 32 + q8);
        }
#pragma unroll
        for (int i = 0; i < 4; ++i)
#pragma unroll
            for (int j = 0; j < 4; ++j)
                acc[i][j] = __builtin_amdgcn_mfma_f32_16x16x32_bf16(aF[i], bF[j], acc[i][j], 0, 0, 0);
        __syncthreads();
    }

    const float* bias = (sel == 0) ? bq : (sel == 1) ? bk : bv;
    short* out = (sel == 0) ? qo : (sel == 1) ? ko : vo;
#pragma unroll
    for (int j = 0; j < 4; ++j) {
        int col = nloc + wn + j * 16 + l15;
        float bval = bias[col];
#pragma unroll
        for (int i = 0; i < 4; ++i) {
#pragma unroll
            for (int r = 0; r < 4; ++r) {
                int row = m0 + wm + i * 16 + quad * 4 + r;
                out[(size_t)row * DIM + col] = f2bf(acc[i][j][r] + bval);
            }
        }
    }
}

// ---------- Wo projection + residual + LN1, fused. NON-ALIASED: X != xout ----------
__global__ __launch_bounds__(256) void gemm_wo_ln(const short* __restrict__ CTX,
                                                  const short* __restrict__ WoT,
                                                  const float* __restrict__ bo,
                                                  const short* __restrict__ X,
                                                  const float* __restrict__ g,
                                                  const float* __restrict__ bta,
                                                  short* __restrict__ xout) {
    __shared__ __align__(16) short lA[128 * 32];   // ctx k-slice     8 KiB
    __shared__ __align__(16) short lB[256 * 32];   // WoT k-slice    16 KiB
    int tid = threadIdx.x;
    int wave = tid >> 6, lane = tid & 63;
    int l15 = lane & 15, quad = lane >> 4;
    int q8 = quad * 8;
    int m0 = blockIdx.x * 128;
    int wr = wave * 32;
    int srow = tid >> 2;
    int skoff = (tid & 3) * 8;
    const short* ag = CTX + (size_t)(m0 + srow) * DIM + skoff;
    const short* bg = WoT + (size_t)srow * DIM + skoff;
    short* lA_dst = lA + tid * 8;
    short* lB_dst = lB + tid * 8;

    floatx4 acc[2][16];
#pragma unroll
    for (int i = 0; i < 2; ++i)
#pragma unroll
        for (int j = 0; j < 16; ++j) acc[i][j] = (floatx4){0.f, 0.f, 0.f, 0.f};

#pragma unroll
    for (int k0 = 0; k0 < DIM; k0 += 32) {
        gload_lds16(ag + k0, lA_dst);
        gload_lds16(ag + (size_t)64 * DIM + k0, lA_dst + 2048);
        gload_lds16(bg + k0, lB_dst);
        gload_lds16(bg + (size_t)64 * DIM + k0, lB_dst + 2048);
        gload_lds16(bg + (size_t)128 * DIM + k0, lB_dst + 4096);
        gload_lds16(bg + (size_t)192 * DIM + k0, lB_dst + 6144);
        __syncthreads();
        short8 aF[2];
#pragma unroll
        for (int t = 0; t < 2; ++t)
            aF[t] = *(const short8*)(lA + (wr + t * 16 + l15) * 32 + q8);
#pragma unroll
        for (int j = 0; j < 16; ++j) {
            short8 bF = *(const short8*)(lB + (j * 16 + l15) * 32 + q8);
#pragma unroll
            for (int i = 0; i < 2; ++i)
                acc[i][j] = __builtin_amdgcn_mfma_f32_16x16x32_bf16(aF[i], bF, acc[i][j], 0, 0, 0);
        }
        __syncthreads();
    }

    float bias[16], gam[16], bet[16];
#pragma unroll
    for (int j = 0; j < 16; ++j) {
        int col = j * 16 + l15;
        bias[j] = bo[col]; gam[j] = g[col]; bet[j] = bta[col];
    }
#pragma unroll
    for (int i = 0; i < 2; ++i) {
#pragma unroll
        for (int r = 0; r < 4; ++r) {
            int row = m0 + wr + i * 16 + quad * 4 + r;
            float v[16], s = 0.f, sq = 0.f;
#pragma unroll
            for (int j = 0; j < 16; ++j) {
                v[j] = acc[i][j][r] + bias[j] + bf2f(X[(size_t)row * DIM + j * 16 + l15]);
                s += v[j]; sq += v[j] * v[j];
            }
            s += __shfl_xor(s, 1); sq += __shfl_xor(sq, 1);
            s += __shfl_xor(s, 2); sq += __shfl_xor(sq, 2);
            s += __shfl_xor(s, 4); sq += __shfl_xor(sq, 4);
            s += __shfl_xor(s, 8); sq += __shfl_xor(sq, 8);
            float mean = s * (1.f / 256.f);
            float var = fmaxf(sq * (1.f / 256.f) - mean * mean, 0.f);
            float rstd = rsqrtf(var + 1e-5f);
#pragma unroll
            for (int j = 0; j < 16; ++j) {
                float y = gam[j] * (v[j] - mean) * rstd + bet[j];
                xout[(size_t)row * DIM + j * 16 + l15] = f2bf(y);
            }
        }
    }
}

// ---------- fused FFN (round-8 verbatim): out = X + relu(X@W1+b1)@W2 + b2 ----------
#define PST 136
__global__ __launch_bounds__(256, 2) void ff_fused(const short* __restrict__ X,
                                                   const short* __restrict__ W1T,
                                                   const float* __restrict__ b1,
                                                   const short* __restrict__ W2T,
                                                   const float* __restrict__ b2,
                                                   short* __restrict__ out) {
    __shared__ __align__(16) short lA[128 * 32];     // x k-slice      8 KiB
    __shared__ __align__(16) short lB[128 * 32];     // W1T k-slice    8 KiB
    __shared__ __align__(16) short lB2[256 * 32];    // W2T k-slice   16 KiB
    __shared__ __align__(16) short lP[128 * PST];    // relu(ff1)     34 KiB
    int tid = threadIdx.x;
    int wave = tid >> 6, lane = tid & 63;
    int l15 = lane & 15, quad = lane >> 4;
    int q8 = quad * 8;
    int m0 = blockIdx.x * 128;
    int wm = (wave & 1) * 64;        // row quadrant (both GEMMs)
    int wf = (wave >> 1) * 64;       // dff cols (GEMM1)
    int wn2 = (wave >> 1) * 128;     // out cols (GEMM2)
    int srow = tid >> 2;
    int spart = (tid & 3) * 8;
    const short* xg = X + (size_t)(m0 + srow) * DIM + spart;
    short* lA_dst = lA + tid * 8;
    short* lB_dst = lB + tid * 8;
    short* lB2_dst = lB2 + tid * 8;

    floatx4 acc2[4][8];
#pragma unroll
    for (int i = 0; i < 4; ++i)
#pragma unroll
        for (int j = 0; j < 8; ++j) acc2[i][j] = (floatx4){0.f, 0.f, 0.f, 0.f};

    for (int f0 = 0; f0 < DFF; f0 += 128) {
        const short* w1g = W1T + (size_t)(f0 + srow) * DIM + spart;
        floatx4 acc1[4][4];
#pragma unroll
        for (int i = 0; i < 4; ++i)
#pragma unroll
            for (int j = 0; j < 4; ++j) acc1[i][j] = (floatx4){0.f, 0.f, 0.f, 0.f};
#pragma unroll
        for (int k0 = 0; k0 < DIM; k0 += 32) {
            gload_lds16(xg + k0, lA_dst);
            gload_lds16(xg + (size_t)64 * DIM + k0, lA_dst + 2048);
            gload_lds16(w1g + k0, lB_dst);
            gload_lds16(w1g + (size_t)64 * DIM + k0, lB_dst + 2048);
            __syncthreads();
            short8 aF[4], bF[4];
#pragma unroll
            for (int t = 0; t < 4; ++t) {
                aF[t] = *(const short8*)(lA + (wm + t * 16 + l15) * 32 + q8);
                bF[t] = *(const short8*)(lB + (wf + t * 16 + l15) * 32 + q8);
            }
#pragma unroll
            for (int i = 0; i < 4; ++i)
#pragma unroll
                for (int j = 0; j < 4; ++j)
                    acc1[i][j] = __builtin_amdgcn_mfma_f32_16x16x32_bf16(aF[i], bF[j], acc1[i][j], 0, 0, 0);
            __syncthreads();
        }
#pragma unroll
        for (int j = 0; j < 4; ++j) {
            int fc = wf + j * 16 + l15;
            float bval = b1[f0 + fc];
#pragma unroll
            for (int i = 0; i < 4; ++i) {
#pragma unroll
                for (int r = 0; r < 4; ++r) {
                    float v = acc1[i][j][r] + bval;
                    lP[(wm + i * 16 + quad * 4 + r) * PST + fc] = f2bf(fmaxf(v, 0.f));
                }
            }
        }
        __syncthreads();
#pragma unroll
        for (int ks = 0; ks < 4; ++ks) {
            const short* w2g = W2T + (size_t)srow * DFF + f0 + ks * 32 + spart;
            gload_lds16(w2g, lB2_dst);
            gload_lds16(w2g + (size_t)64 * DFF, lB2_dst + 2048);
            gload_lds16(w2g + (size_t)128 * DFF, lB2_dst + 4096);
            gload_lds16(w2g + (size_t)192 * DFF, lB2_dst + 6144);
            __syncthreads();
            short8 aP[4], bW[8];
#pragma unroll
            for (int t = 0; t < 4; ++t)
                aP[t] = *(const short8*)(lP + (wm + t * 16 + l15) * PST + ks * 32 + q8);
#pragma unroll
            for (int j = 0; j < 8; ++j)
                bW[j] = *(const short8*)(lB2 + (wn2 + j * 16 + l15) * 32 + q8);
#pragma unroll
            for (int i = 0; i < 4; ++i)
#pragma unroll
                for (int j = 0; j < 8; ++j)
                    acc2[i][j] = __builtin_amdgcn_mfma_f32_16x16x32_bf16(aP[i], bW[j], acc2[i][j], 0, 0, 0);
            __syncthreads();
        }
    }

#pragma unroll
    for (int j = 0; j < 8; ++j) {
        int col = wn2 + j * 16 + l15;
        float bval = b2[col];
#pragma unroll
        for (int i = 0; i < 4; ++i) {
#pragma unroll
            for (int r = 0; r < 4; ++r) {
                int row = m0 + wm + i * 16 + quad * 4 + r;
                float v = acc2[i][j][r] + bval + bf2f(X[(size_t)row * DIM + col]);
                out[(size_t)row * DIM + col] = f2bf(v);
            }
        }
    }
}

// ---------- V transpose: v [M,256] -> vT [B*H][DH][SPAD] ----------
__global__ __launch_bounds__(256) void transpose_v(const short* __restrict__ v,
                                                   short* __restrict__ vT) {
    __shared__ short lds[32][33];
    int pair = blockIdx.y;
    int b = pair >> 1, h = pair & 1;
    int st = (blockIdx.x & 15) * 32;
    int dt = (blockIdx.x >> 4) * 32;
    int tid = threadIdx.x;
    int sl = tid >> 3, dl = (tid & 7) * 4;
    const short* src = v + ((size_t)(b * SPAD + st + sl)) * DIM + h * DH + dt + dl;
    short4v val = *(const short4v*)src;
#pragma unroll
    for (int j = 0; j < 4; ++j) lds[sl][dl + j] = val[j];
    __syncthreads();
    int drow = tid >> 3, scol = (tid & 7) * 4;
    short* dst = vT + (size_t)pair * DH * SPAD + (size_t)(dt + drow) * SPAD + st + scol;
#pragma unroll
    for (int j = 0; j < 4; ++j) dst[j] = lds[scol + j][drow];
}

// ---------- fused attention: S kept in LDS, never hits HBM ----------
// grid (4 m-tiles, B*H pairs). Per kt (128-key chunk): QK via score_exp's
// staged GEMM, exp+mask -> lS (C-layout scatter, ff_fused's lP pattern),
// barrier, then attn_pv's PV GEMM with lS as A operand; rowsum from
// A-fragments in-loop; final /rowsum epilogue identical to attn_pv.
#define AST 136
__global__ __launch_bounds__(256) void attn_fused(const short* __restrict__ q,
                                                  const short* __restrict__ k,
                                                  const short* __restrict__ vT,
                                                  short* __restrict__ ctx) {
    __shared__ __align__(16) short lA[128 * 32];   //  8 KiB
    __shared__ __align__(16) short lB[128 * 32];   //  8 KiB (K slice, then V slice)
    __shared__ __align__(16) short lS[128 * AST];  // 34 KiB exp(S) chunk
    int tid = threadIdx.x;
    int wave = tid >> 6, lane = tid & 63;
    int l15 = lane & 15, quad = lane >> 4;
    int q8 = quad * 8;
    int pair = blockIdx.y;
    int b = pair >> 1, h = pair & 1;
    int m0 = blockIdx.x * 128;
    int wm = (wave & 1) * 64;
    int wn = (wave >> 1) * 64;

    const short* Qb = q + ((size_t)b * SPAD) * DIM + h * DH;
    const short* Kb = k + ((size_t)b * SPAD) * DIM + h * DH;
    const short* Vb = vT + (size_t)pair * DH * SPAD;
    int srow = tid >> 2;
    int skoff = (tid & 3) * 8;
    short* lA_dst = lA + tid * 8;
    short* lB_dst = lB + tid * 8;
    const size_t rstep = (size_t)64 * DIM;
    const short* ag = Qb + (size_t)(m0 + srow) * DIM + skoff;
    const float scale = 0.08838834764831845f;  // 1/sqrt(128)

    floatx4 oacc[4][4];
#pragma unroll
    for (int i = 0; i < 4; ++i)
#pragma unroll
        for (int j = 0; j < 4; ++j) oacc[i][j] = (floatx4){0.f, 0.f, 0.f, 0.f};
    float rsum[4] = {0.f, 0.f, 0.f, 0.f};

    for (int kt = 0; kt < 4; ++kt) {
        // ---- QK: sacc = Q[m-tile] . K[kt-chunk]^T (score_exp body) ----
        const short* bg = Kb + (size_t)(kt * 128 + srow) * DIM + skoff;
        floatx4 sacc[4][4];
#pragma unroll
        for (int i = 0; i < 4; ++i)
#pragma unroll
            for (int j = 0; j < 4; ++j) sacc[i][j] = (floatx4){0.f, 0.f, 0.f, 0.f};
#pragma unroll
        for (int k0 = 0; k0 < DH; k0 += 32) {
            gload_lds16(ag + k0, lA_dst);
            gload_lds16(ag + rstep + k0, lA_dst + 2048);
            gload_lds16(bg + k0, lB_dst);
            gload_lds16(bg + rstep + k0, lB_dst + 2048);
            __syncthreads();
            short8 aF[4], bF[4];
#pragma unroll
            for (int t = 0; t < 4; ++t) {
                aF[t] = *(const short8*)(lA + (wm + t * 16 + l15) * 32 + q8);
                bF[t] = *(const short8*)(lB + (wn + t * 16 + l15) * 32 + q8);
            }
#pragma unroll
            for (int i = 0; i < 4; ++i)
#pragma unroll
                for (int j = 0; j < 4; ++j)
                    sacc[i][j] = __builtin_amdgcn_mfma_f32_16x16x32_bf16(aF[i], bF[j], sacc[i][j], 0, 0, 0);
            __syncthreads();
        }
        // ---- exp + mask -> lS (C-layout scatter) ----
#pragma unroll
        for (int j = 0; j < 4; ++j) {
            int col = wn + j * 16 + l15;
            float keep = (kt * 128 + col < MAXV) ? 1.f : 0.f;
#pragma unroll
            for (int i = 0; i < 4; ++i) {
#pragma unroll
                for (int r = 0; r < 4; ++r) {
                    lS[(wm + i * 16 + quad * 4 + r) * AST + col] =
                        f2bf(keep * __expf(sacc[i][j][r] * scale));
                }
            }
        }
        __syncthreads();
        // ---- PV: oacc += lS . V[kt-chunk] (attn_pv body) ----
#pragma unroll
        for (int ks = 0; ks < 4; ++ks) {
            const short* vg = Vb + (size_t)srow * SPAD + kt * 128 + ks * 32 + skoff;
            gload_lds16(vg, lB_dst);
            gload_lds16(vg + (size_t)64 * SPAD, lB_dst + 2048);
            __syncthreads();
            short8 aP[4], bV[4];
#pragma unroll
            for (int t = 0; t < 4; ++t) {
                aP[t] = *(const short8*)(lS + (wm + t * 16 + l15) * AST + ks * 32 + q8);
                bV[t] = *(const short8*)(lB + (wn + t * 16 + l15) * 32 + q8);
            }
#pragma unroll
            for (int i = 0; i < 4; ++i) {
                float s = 0.f;
#pragma unroll
                for (int e = 0; e < 8; ++e) s += bf2f(aP[i][e]);
                rsum[i] += s;
            }
#pragma unroll
            for (int i = 0; i < 4; ++i)
#pragma unroll
                for (int j = 0; j < 4; ++j)
                    oacc[i][j] = __builtin_amdgcn_mfma_f32_16x16x32_bf16(aP[i], bV[j], oacc[i][j], 0, 0, 0);
            __syncthreads();
        }
    }

    // ---- epilogue (attn_pv verbatim): /rowsum, write ctx ----
#pragma unroll
    for (int i = 0; i < 4; ++i) {
        rsum[i] += __shfl_xor(rsum[i], 16);
        rsum[i] += __shfl_xor(rsum[i], 32);
    }
    short* outb = ctx + ((size_t)(b * SPAD + m0)) * DIM + h * DH;
#pragma unroll
    for (int i = 0; i < 4; ++i) {
#pragma unroll
        for (int r = 0; r < 4; ++r) {
            float inv = 1.f / __shfl(rsum[i], quad * 4 + r);
#pragma unroll
            for (int j = 0; j < 4; ++j) {
                int col = wn + j * 16 + l15;
                int row = wm + i * 16 + quad * 4 + r;
                outb[(size_t)row * DIM + col] = f2bf(oacc[i][j][r] * inv);
            }
        }
    }
}

// ---------- LayerNorm (round-8 verbatim) ----------
__global__ __launch_bounds__(256) void ln_k(const short* __restrict__ hbuf,
                                            const float* __restrict__ g,
                                            const float* __restrict__ bta,
                                            short* __restrict__ xout,
                                            float* __restrict__ fout) {
    __shared__ float red[4][2];
    int row = blockIdx.x;
    int d = threadIdx.x;
    float v = bf2f(hbuf[(size_t)row * DIM + d]);
    float s = v, sq = v * v;
#pragma unroll
    for (int off = 1; off < 64; off <<= 1) {
        s += __shfl_xor(s, off);
        sq += __shfl_xor(sq, off);
    }
    int wave = threadIdx.x >> 6, lane = threadIdx.x & 63;
    if (lane == 0) { red[wave][0] = s; red[wave][1] = sq; }
    __syncthreads();
    float ts = red[0][0] + red[1][0] + red[2][0] + red[3][0];
    float tq = red[0][1] + red[1][1] + red[2][1] + red[3][1];
    float mean = ts * (1.f / 256.f);
    float var = tq * (1.f / 256.f) - mean * mean;
    var = fmaxf(var, 0.f);
    float rstd = rsqrtf(var + 1e-5f);
    float y = g[d] * (v - mean) * rstd + bta[d];
    xout[(size_t)row * DIM + d] = f2bf(y);
    if (fout) {
        int p = row & 511;
        if (p < MAXV) {
            int b = row >> 9;
            fout[((size_t)b * MAXV + p) * DIM + d] = y;
        }
    }
}

extern "C" void kernel_launch(void* const* d_in, const int* in_sizes, int n_in,
                              void* d_out, int out_size, void* d_ws, size_t ws_size,
                              hipStream_t stream) {
    const int*   all_codes = (const int*)d_in[0];
    const float* times = (const float*)d_in[3];
    const float* cemb  = (const float*)d_in[4];
    const float* pemb  = (const float*)d_in[5];
    const float* Wq = (const float*)d_in[6];
    const float* Wk = (const float*)d_in[7];
    const float* Wv = (const float*)d_in[8];
    const float* Wo = (const float*)d_in[9];
    const float* bq = (const float*)d_in[10];
    const float* bk = (const float*)d_in[11];
    const float* bv = (const float*)d_in[12];
    const float* bo = (const float*)d_in[13];
    const float* ln1g = (const float*)d_in[14];
    const float* ln1b = (const float*)d_in[15];
    const float* W1 = (const float*)d_in[16];
    const float* b1 = (const float*)d_in[17];
    const float* W2 = (const float*)d_in[18];
    const float* b2 = (const float*)d_in[19];
    const float* ln2g = (const float*)d_in[20];
    const float* ln2b = (const float*)d_in[21];

    char* ws = (char*)d_ws;
    short* wqkvT = (short*)ws;                    // [2][768*256]
    short* woT   = wqkvT + 2 * 196608;            // [2][256*256]
    short* w1T   = woT + 2 * 65536;               // [2][1024*256]
    short* w2T   = w1T + 2 * 262144;              // [2][256*1024]

    const size_t SLOT = (size_t)MROWS * DIM;
    short* xb = (short*)(ws + (4u << 20));
    short* C0 = xb + SLOT;     // q -> h1 (LN1 out)
    short* C1 = C0 + SLOT;     // k
    short* C2 = C1 + SLOT;     // v
    short* C3 = C2 + SLOT;     // ctx
    short* C4 = C3 + SLOT;     // vT / h2

    for (int l = 0; l < NLAYERS; ++l) {
        short* qkv_l = wqkvT + (size_t)l * 196608;
        wtrans<<<256, 256, 0, stream>>>(Wq + (size_t)l * 65536, qkv_l, 256, 256);
        wtrans<<<256, 256, 0, stream>>>(Wk + (size_t)l * 65536, qkv_l + 65536, 256, 256);
        wtrans<<<256, 256, 0, stream>>>(Wv + (size_t)l * 65536, qkv_l + 131072, 256, 256);
        wtrans<<<256, 256, 0, stream>>>(Wo + (size_t)l * 65536, woT + (size_t)l * 65536, 256, 256);
        wtrans<<<1024, 256, 0, stream>>>(W1 + (size_t)l * 262144, w1T + (size_t)l * 262144, 256, 1024);
        wtrans<<<1024, 256, 0, stream>>>(W2 + (size_t)l * 262144, w2T + (size_t)l * 262144, 1024, 256);
    }

    build_x<<<MROWS, 256, 0, stream>>>(all_codes, times, cemb, pemb, xb);

    for (int l = 0; l < NLAYERS; ++l) {
        const short* qkv_l = wqkvT + (size_t)l * 196608;
        const short* wo_l = woT + (size_t)l * 65536;
        const short* w1_l = w1T + (size_t)l * 262144;
        const short* w2_l = w2T + (size_t)l * 262144;

        gemm_qkv<<<dim3(6, 512), 256, 0, stream>>>(xb, qkv_l, bq + l * 256, bk + l * 256,
                                                   bv + l * 256, C0, C1, C2);
        transpose_v<<<dim3(64, BATCH * NH), 256, 0, stream>>>(C2, C4);
        // single-launch fused attention (S stays in LDS)
        attn_fused<<<dim3(4, BATCH * NH), 256, 0, stream>>>(C0, C1, C4, C3);
        // h1 = LN1(x + ctx@Wo + bo): reads C3 + xb, writes C0. No aliasing.
        gemm_wo_ln<<<512, 256, 0, stream>>>(C3, wo_l, bo + l * 256, xb,
                                            ln1g + l * 256, ln1b + l * 256, C0);
        // h2 = h1 + ffn(h1): reads C0, writes C4. No aliasing.
        ff_fused<<<512, 256, 0, stream>>>(C0, w1_l, b1 + l * 1024, w2_l, b2 + l * 256, C4);
        // x = LN2(h2) -> xb (+ f32 d_out on last layer)
        ln_k<<<MROWS, 256, 0, stream>>>(C4, ln2g + l * 256, ln2b + l * 256, xb,
                                        (l == NLAYERS - 1) ? (float*)d_out : nullptr);
    }
}